// Round 1
// 84.184 us; speedup vs baseline: 1.0053x; 1.0053x over previous
//
#include <hip/hip_runtime.h>

// Blobber: out = sig2(box3(sig1(box3(in)))) — the reference's 4 iterations all
// restart from `inputs`, so they collapse to one iteration.
// in/out: 32 x 1 x 512 x 512 fp32.
//
// R5: latency/occupancy attack. R4's verified kernel (BH=8, all 12 rows
// up-front in registers) was ~40 us vs a ~13 us memory roofline with only
// 2048 waves (2/SIMD) and ~96 VGPRs of row cache. This version:
//   - BH=4 -> 4096 waves (16/CU) for 2x latency hiding via TLP
//   - rolling 3-row input window (a,b,c) + 1-row prefetch (n) instead of the
//     up-front 8-row cache: ~32 VGPRs of row state, keeps occupancy
//     grid-limited, not register-limited
//   - the 4 waves of a block are ADJACENT bands of one image -> the 4 halo
//     rows re-read per band hit L1/L2, so HBM fetch stays near compulsory
// Pipeline body (shuffle seam handling, s1/h2/out math) is byte-identical to
// the verified R4 kernel.
//
// Per s1 row r: v3 = in(r-1)+in(r)+in(r+1) (rows zero-padded);
// s1 = sig1(h3(v3)), forced 0 for OOB rows (conv2 zero-pads s1 itself,
// NOT sig1(0)=4.5e-5); h2 = h3(s1); out(y) = sig2(h2(y-1)+h2(y)+h2(y+1)).

#define IMG 512
#define BH  4             // output rows per wave
#define NIT (BH + 2)      // 6 s1/h2 rows

// sigmoid((sum9/9 - c)*1000) = sigmoid(fma(sum9, 1000/9, -1000c))
__device__ __forceinline__ float steep_sig(float sum9, float bias) {
    float x = fmaf(sum9, 1000.0f / 9.0f, bias);
    return __builtin_amdgcn_rcpf(1.0f + __expf(-x));
}

__device__ __forceinline__ float4 f4add3(float4 a, float4 b, float4 c) {
    return make_float4(a.x + b.x + c.x, a.y + b.y + c.y,
                       a.z + b.z + c.z, a.w + b.w + c.w);
}

__global__ __launch_bounds__(256) void blobber_fused(const float* __restrict__ in,
                                                     float* __restrict__ out) {
    const int tid  = threadIdx.x;
    const int lane = tid & 63;
    const int gw   = blockIdx.x * 4 + (tid >> 6);   // 4096 waves
    const int band = gw & 127;                      // 128 bands x 4 rows
    const int img  = gw >> 7;                       // 32 images
    const int y0   = band * BH;

    const int colL = 4 * lane;         // L half: cols 0..255, coalesced
    const int colR = 256 + 4 * lane;   // R half: cols 256..511, coalesced

    const float* ip = in  + (size_t)img * (IMG * IMG);
    float*       op = out + (size_t)img * (IMG * IMG);

    const float4 z4 = make_float4(0.f, 0.f, 0.f, 0.f);

    // ---- rolling window: a,b,c = input rows r-1, r, r+1 for current s ----
    // prologue: rows y0-2, y0-1, y0 (zero for OOB rows)
    float4 aL = z4, bL = z4, cL = z4, aR = z4, bR = z4, cR = z4;
    if (y0 - 2 >= 0) {                              // wave-uniform
        aL = *(const float4*)(ip + (y0 - 2) * IMG + colL);
        aR = *(const float4*)(ip + (y0 - 2) * IMG + colR);
    }
    if (y0 - 1 >= 0) {                              // wave-uniform
        bL = *(const float4*)(ip + (y0 - 1) * IMG + colL);
        bR = *(const float4*)(ip + (y0 - 1) * IMG + colR);
    }
    cL = *(const float4*)(ip + y0 * IMG + colL);    // y0 always in range
    cR = *(const float4*)(ip + y0 * IMG + colR);

    float4 h2mL = z4, h2cL = z4, h2mR = z4, h2cR = z4;

    #pragma unroll
    for (int s = 0; s < NIT; ++s) {
        const int r = y0 - 1 + s;                   // s1/h2 row being produced

        // prefetch input row r+2 (becomes c after the shift, used next iter)
        float4 nL = z4, nR = z4;
        if (s < NIT - 1) {
            const int pr = r + 2;                   // y0+1+s, always >= 1
            if (pr < IMG) {                         // wave-uniform
                nL = *(const float4*)(ip + pr * IMG + colL);
                nR = *(const float4*)(ip + pr * IMG + colR);
            }
        }

        // vertical 3-sum (input rows r-1..r+1)
        float4 vL = f4add3(aL, bL, cL);
        float4 vR = f4add3(aR, bR, cR);

        // horizontal neighbors of v3 (full-exec shuffles, per-lane fixups)
        float Llft = __shfl_up(vL.w, 1);
        float Lrgt = __shfl_down(vL.x, 1);
        float Rlft = __shfl_up(vR.w, 1);
        float Rrgt = __shfl_down(vR.x, 1);
        float c256 = __shfl(vR.x, 0);               // v3 at col 256
        float c255 = __shfl(vL.w, 63);              // v3 at col 255
        if (lane == 0)  { Llft = 0.0f;  Rlft = c255; }   // col -1 -> 0
        if (lane == 63) { Lrgt = c256;  Rrgt = 0.0f; }   // col 512 -> 0

        // stage 1: s1 = sig1(h3(v3)); OOB rows are literal 0
        float4 s1L, s1R;
        if ((unsigned)r < IMG) {                    // wave-uniform
            s1L.x = steep_sig(Llft + vL.x + vL.y, -10.0f);
            s1L.y = steep_sig(vL.x + vL.y + vL.z, -10.0f);
            s1L.z = steep_sig(vL.y + vL.z + vL.w, -10.0f);
            s1L.w = steep_sig(vL.z + vL.w + Lrgt, -10.0f);
            s1R.x = steep_sig(Rlft + vR.x + vR.y, -10.0f);
            s1R.y = steep_sig(vR.x + vR.y + vR.z, -10.0f);
            s1R.z = steep_sig(vR.y + vR.z + vR.w, -10.0f);
            s1R.w = steep_sig(vR.z + vR.w + Rrgt, -10.0f);
        } else {
            s1L = z4; s1R = z4;
        }

        // stage 2 horizontal: h2 = h3(s1)
        float sLl = __shfl_up(s1L.w, 1);
        float sLr = __shfl_down(s1L.x, 1);
        float sRl = __shfl_up(s1R.w, 1);
        float sRr = __shfl_down(s1R.x, 1);
        float s256 = __shfl(s1R.x, 0);              // s1 at col 256
        float s255 = __shfl(s1L.w, 63);             // s1 at col 255
        if (lane == 0)  { sLl = 0.0f;  sRl = s255; }
        if (lane == 63) { sLr = s256;  sRr = 0.0f; }

        float4 h2pL, h2pR;
        h2pL.x = sLl   + s1L.x + s1L.y;
        h2pL.y = s1L.x + s1L.y + s1L.z;
        h2pL.z = s1L.y + s1L.z + s1L.w;
        h2pL.w = s1L.z + s1L.w + sLr;
        h2pR.x = sRl   + s1R.x + s1R.y;
        h2pR.y = s1R.x + s1R.y + s1R.z;
        h2pR.z = s1R.y + s1R.z + s1R.w;
        h2pR.w = s1R.z + s1R.w + sRr;

        // output row r-1 = sig2(vertical 3-sum of h2 rows r-2..r)
        if (s >= 2) {
            const int oy = r - 1;                   // y0 .. y0+3
            float4 oL, oR;
            oL.x = steep_sig(h2mL.x + h2cL.x + h2pL.x, -900.0f);
            oL.y = steep_sig(h2mL.y + h2cL.y + h2pL.y, -900.0f);
            oL.z = steep_sig(h2mL.z + h2cL.z + h2pL.z, -900.0f);
            oL.w = steep_sig(h2mL.w + h2cL.w + h2pL.w, -900.0f);
            oR.x = steep_sig(h2mR.x + h2cR.x + h2pR.x, -900.0f);
            oR.y = steep_sig(h2mR.y + h2cR.y + h2pR.y, -900.0f);
            oR.z = steep_sig(h2mR.z + h2cR.z + h2pR.z, -900.0f);
            oR.w = steep_sig(h2mR.w + h2cR.w + h2pR.w, -900.0f);
            *(float4*)(op + oy * IMG + colL) = oL;
            *(float4*)(op + oy * IMG + colR) = oR;
        }

        h2mL = h2cL; h2cL = h2pL;
        h2mR = h2cR; h2cR = h2pR;

        // shift the rolling window
        aL = bL; bL = cL; cL = nL;
        aR = bR; bR = cR; cR = nR;
    }
}

extern "C" void kernel_launch(void* const* d_in, const int* in_sizes, int n_in,
                              void* d_out, int out_size, void* d_ws, size_t ws_size,
                              hipStream_t stream) {
    const float* in  = (const float*)d_in[0];
    float*       out = (float*)d_out;
    // 4096 waves = 1024 blocks x 4 waves (32 imgs x 128 bands)
    blobber_fused<<<dim3(1024), dim3(256), 0, stream>>>(in, out);
}

// Round 3
// 82.421 us; speedup vs baseline: 1.0268x; 1.0214x over previous
//
#include <hip/hip_runtime.h>

// Blobber: out = sig2(box3(sig1(box3(in)))) — the reference's 4 iterations all
// restart from `inputs`, so they collapse to one iteration.
// in/out: 32 x 1 x 512 x 512 fp32.
//
// R7 = R6 with the compile fix (__builtin_nontemporal_store needs a clang
// ext_vector type, not HIP's float4 class).
//
// R6 theory: R5 (rolling window, 4096 waves) was ~41 us and occupancy-
// invariant -> bottleneck is the 144 ds_bpermute/wave with 24 serialized
// lgkmcnt waits per iteration, not latency hiding. This version replaces ALL
// __shfl traffic with a wave-private padded LDS row buffer:
//   - per stage: 2x ds_write_b128 (own 4 cols per half), wave_barrier (free
//     compiler fence; per-wave DS pipe is in-order in HW), then 2 scalar
//     ds_read_b32 per half for the col-1 / col+4 neighbors.
//   - 520-float row = 4 zero pad | 512 cols | 4 zero pad: image edges AND the
//     L/R half seam are handled with no broadcasts, no cndmask fixups.
//   - DS ops: 24 bpermute -> 8/iter; waits: 24 -> 2/iter.
// Keeps R5's BH=4 rolling input window (4096 waves, 16/CU) and nontemporal
// output stores (don't evict halo rows from L2).
//
// Per s1 row r: v3 = in(r-1)+in(r)+in(r+1) (rows zero-padded);
// s1 = sig1(h3(v3)), forced 0 for OOB rows (conv2 zero-pads s1 itself,
// NOT sig1(0)=4.5e-5); h2 = h3(s1); out(y) = sig2(h2(y-1)+h2(y)+h2(y+1)).

#define IMG 512
#define BH  4             // output rows per wave
#define NIT (BH + 2)      // 6 s1/h2 rows
#define BUFW 520          // 4 pad | 512 | 4 pad

typedef float vf4 __attribute__((ext_vector_type(4)));   // nontemporal-store-able

// sigmoid((sum9/9 - c)*1000) = sigmoid(fma(sum9, 1000/9, -1000c))
__device__ __forceinline__ float steep_sig(float sum9, float bias) {
    float x = fmaf(sum9, 1000.0f / 9.0f, bias);
    return __builtin_amdgcn_rcpf(1.0f + __expf(-x));
}

__device__ __forceinline__ float4 f4add3(float4 a, float4 b, float4 c) {
    return make_float4(a.x + b.x + c.x, a.y + b.y + c.y,
                       a.z + b.z + c.z, a.w + b.w + c.w);
}

__device__ __forceinline__ void nt_store4(float* p, float x, float y, float z, float w) {
    vf4 v = {x, y, z, w};
    __builtin_nontemporal_store(v, (vf4*)p);
}

__global__ __launch_bounds__(256) void blobber_fused(const float* __restrict__ in,
                                                     float* __restrict__ out) {
    __shared__ float vbuf[4][BUFW];   // v3 row, one per wave
    __shared__ float sbuf[4][BUFW];   // s1 row, one per wave

    const int tid  = threadIdx.x;
    const int lane = tid & 63;
    const int wid  = tid >> 6;
    const int gw   = blockIdx.x * 4 + wid;          // 4096 waves
    const int band = gw & 127;                      // 128 bands x 4 rows
    const int img  = gw >> 7;                       // 32 images
    const int y0   = band * BH;

    float* vb = vbuf[wid];
    float* sb = sbuf[wid];

    // zero the pads once (cols -4..-1 and 512..515); never overwritten
    if (lane < 4) {
        vb[lane] = 0.0f; vb[516 + lane] = 0.0f;
        sb[lane] = 0.0f; sb[516 + lane] = 0.0f;
    }
    __builtin_amdgcn_wave_barrier();

    const int colL = 4 * lane;         // L half: cols 0..255, coalesced
    const int colR = 256 + 4 * lane;   // R half: cols 256..511, coalesced
    const int bL   = 4 + colL;         // LDS index of own L cols
    const int bR   = 4 + colR;         // LDS index of own R cols

    const float* ip = in  + (size_t)img * (IMG * IMG);
    float*       op = out + (size_t)img * (IMG * IMG);

    const float4 z4 = make_float4(0.f, 0.f, 0.f, 0.f);

    // ---- rolling window: a,b,c = input rows r-1, r, r+1 for current s ----
    float4 aL = z4, bLw = z4, cL = z4, aR = z4, bRw = z4, cR = z4;
    if (y0 - 2 >= 0) {                              // wave-uniform
        aL = *(const float4*)(ip + (y0 - 2) * IMG + colL);
        aR = *(const float4*)(ip + (y0 - 2) * IMG + colR);
    }
    if (y0 - 1 >= 0) {                              // wave-uniform
        bLw = *(const float4*)(ip + (y0 - 1) * IMG + colL);
        bRw = *(const float4*)(ip + (y0 - 1) * IMG + colR);
    }
    cL = *(const float4*)(ip + y0 * IMG + colL);    // y0 always in range
    cR = *(const float4*)(ip + y0 * IMG + colR);

    float4 h2mL = z4, h2cL = z4, h2mR = z4, h2cR = z4;

    #pragma unroll
    for (int s = 0; s < NIT; ++s) {
        const int r = y0 - 1 + s;                   // s1/h2 row being produced

        // prefetch input row r+2 (becomes c after the shift)
        float4 nL = z4, nR = z4;
        if (s < NIT - 1) {
            const int pr = r + 2;                   // y0+1+s, always >= 1
            if (pr < IMG) {                         // wave-uniform
                nL = *(const float4*)(ip + pr * IMG + colL);
                nR = *(const float4*)(ip + pr * IMG + colR);
            }
        }

        // vertical 3-sum (input rows r-1..r+1)
        float4 vL = f4add3(aL, bLw, cL);
        float4 vR = f4add3(aR, bRw, cR);

        // publish v3 row to wave-private LDS row buffer
        *(float4*)(vb + bL) = vL;
        *(float4*)(vb + bR) = vR;
        __builtin_amdgcn_wave_barrier();
        // neighbors: v3[col-1], v3[col+4] per half (pads give image edges;
        // the 255/256 seam is just the other half's write)
        float vLl = vb[bL - 1], vLr = vb[bL + 4];
        float vRl = vb[bR - 1], vRr = vb[bR + 4];

        // stage 1: s1 = sig1(h3(v3)); OOB rows are literal 0
        float4 s1L, s1R;
        if ((unsigned)r < IMG) {                    // wave-uniform
            s1L.x = steep_sig(vLl  + vL.x + vL.y, -10.0f);
            s1L.y = steep_sig(vL.x + vL.y + vL.z, -10.0f);
            s1L.z = steep_sig(vL.y + vL.z + vL.w, -10.0f);
            s1L.w = steep_sig(vL.z + vL.w + vLr,  -10.0f);
            s1R.x = steep_sig(vRl  + vR.x + vR.y, -10.0f);
            s1R.y = steep_sig(vR.x + vR.y + vR.z, -10.0f);
            s1R.z = steep_sig(vR.y + vR.z + vR.w, -10.0f);
            s1R.w = steep_sig(vR.z + vR.w + vRr,  -10.0f);
        } else {
            s1L = z4; s1R = z4;
        }

        // publish s1 row, read its neighbors
        *(float4*)(sb + bL) = s1L;
        *(float4*)(sb + bR) = s1R;
        __builtin_amdgcn_wave_barrier();
        float sLl = sb[bL - 1], sLr = sb[bL + 4];
        float sRl = sb[bR - 1], sRr = sb[bR + 4];

        // stage 2 horizontal: h2 = h3(s1)
        float4 h2pL, h2pR;
        h2pL.x = sLl   + s1L.x + s1L.y;
        h2pL.y = s1L.x + s1L.y + s1L.z;
        h2pL.z = s1L.y + s1L.z + s1L.w;
        h2pL.w = s1L.z + s1L.w + sLr;
        h2pR.x = sRl   + s1R.x + s1R.y;
        h2pR.y = s1R.x + s1R.y + s1R.z;
        h2pR.z = s1R.y + s1R.z + s1R.w;
        h2pR.w = s1R.z + s1R.w + sRr;

        // output row r-1 = sig2(vertical 3-sum of h2 rows r-2..r)
        if (s >= 2) {
            const int oy = r - 1;                   // y0 .. y0+3
            nt_store4(op + oy * IMG + colL,
                      steep_sig(h2mL.x + h2cL.x + h2pL.x, -900.0f),
                      steep_sig(h2mL.y + h2cL.y + h2pL.y, -900.0f),
                      steep_sig(h2mL.z + h2cL.z + h2pL.z, -900.0f),
                      steep_sig(h2mL.w + h2cL.w + h2pL.w, -900.0f));
            nt_store4(op + oy * IMG + colR,
                      steep_sig(h2mR.x + h2cR.x + h2pR.x, -900.0f),
                      steep_sig(h2mR.y + h2cR.y + h2pR.y, -900.0f),
                      steep_sig(h2mR.z + h2cR.z + h2pR.z, -900.0f),
                      steep_sig(h2mR.w + h2cR.w + h2pR.w, -900.0f));
        }

        h2mL = h2cL; h2cL = h2pL;
        h2mR = h2cR; h2cR = h2pR;

        // shift the rolling window
        aL = bLw; bLw = cL; cL = nL;
        aR = bRw; bRw = cR; cR = nR;
        // next iteration's LDS writes must not pass this iteration's reads
        __builtin_amdgcn_wave_barrier();
    }
}

extern "C" void kernel_launch(void* const* d_in, const int* in_sizes, int n_in,
                              void* d_out, int out_size, void* d_ws, size_t ws_size,
                              hipStream_t stream) {
    const float* in  = (const float*)d_in[0];
    float*       out = (float*)d_out;
    // 4096 waves = 1024 blocks x 4 waves (32 imgs x 128 bands)
    blobber_fused<<<dim3(1024), dim3(256), 0, stream>>>(in, out);
}